// Round 10
// baseline (19.512 us; speedup 1.0000x reference)
//
#include <hip/hip_runtime.h>

typedef short s16x8 __attribute__((ext_vector_type(8)));
typedef float f32x4 __attribute__((ext_vector_type(4)));

__device__ __forceinline__ short f2bf(float f) {  // RNE f32->bf16
  union { float f; unsigned u; } cv;
  cv.f = f;
  unsigned u = cv.u;
  u = (u + 0x7FFFu + ((u >> 16) & 1u)) >> 16;
  return (short)u;
}
// pack two f32 -> bf16x2 by truncation (low elem = lo)
__device__ __forceinline__ unsigned pk2(float lo, float hi) {
  union { float f; unsigned u; } a, b;
  a.f = lo;
  b.f = hi;
  return (a.u >> 16) | (b.u & 0xFFFF0000u);
}

// ---------------------------------------------------------------------------
// K0: McT[m*40 + e*5 + a] = bf16(sum_n adj_w[e,m,n]*adj_a[a,n]); rows
// [25,40) zeroed by e==0 blocks. 80 blocks (e x 16 mgroups) x 256 threads;
// 32 lanes cooperate per m (float4 each) -> adj_w read spread over 80 CUs.
// ---------------------------------------------------------------------------
__global__ __launch_bounds__(256) void precomp_McT(
    const float* __restrict__ adj_w, const float* __restrict__ adj_a,
    unsigned short* __restrict__ McT) {
  __shared__ float As[5][128];
  const int t = threadIdx.x;
  const int e = blockIdx.x >> 4, mg = blockIdx.x & 15;
  for (int idx = t; idx < 640; idx += 256) As[idx >> 7][idx & 127] = adj_a[idx];
  __syncthreads();
  const int m = mg * 8 + (t >> 5), l2 = t & 31;
  const float4 wv = *(const float4*)(adj_w + (size_t)e * 16384 +
                                     (size_t)m * 128 + l2 * 4);
  const float wa[4] = {wv.x, wv.y, wv.z, wv.w};
  float acc[5] = {0.f, 0.f, 0.f, 0.f, 0.f};
#pragma unroll
  for (int q = 0; q < 4; ++q) {
    const int n = l2 * 4 + q;
#pragma unroll
    for (int a = 0; a < 5; ++a) acc[a] = fmaf(wa[q], As[a][n], acc[a]);
  }
#pragma unroll
  for (int d = 1; d < 32; d <<= 1)
#pragma unroll
    for (int a = 0; a < 5; ++a) acc[a] += __shfl_xor(acc[a], d);
  if (l2 == 0) {
#pragma unroll
    for (int a = 0; a < 5; ++a)
      McT[m * 40 + e * 5 + a] = (unsigned short)f2bf(acc[a]);
    if (e == 0)
#pragma unroll
      for (int r = 25; r < 40; ++r) McT[m * 40 + r] = 0;
  }
}

// ---------------------------------------------------------------------------
// Main: one block per batch b (256 blocks x 512 threads, 1 block/CU).
//   T0: issue bfm (8 int4), McT/a_bfm, adj (8 float4) -- consumed in order.
//   hist (register byte-counters + shfl + LDS reduce) -> P scatter (in-LDS,
//   no global roundtrip) -> Q = adj@P (8 MFMA/wave) -> wave-local transpose
//   -> out = (McT_rows)@Q^T (8 MFMA, operand-swapped -> float4 stores).
// Raw s_barrier + lgkmcnt-only waits keep adj in flight until the pack.
// ---------------------------------------------------------------------------
__global__ __launch_bounds__(512, 2) void fused_batch_kernel(
    const int* __restrict__ bfm, const float* __restrict__ adj,
    const int* __restrict__ a_bfm, const unsigned short* __restrict__ McT,
    float* __restrict__ out) {
  __shared__ unsigned red[8][32][4][2];                     // 8 KB
  __shared__ __align__(16) unsigned short Pt[32 * 128];     // 8 KB, XOR-swz
  __shared__ __align__(16) unsigned short Mt[128 * 40];     // 10 KB
  __shared__ __align__(16) unsigned short Qs[8 * 16 * 40];  // 10 KB

  const int b = blockIdx.x;
  const int t = threadIdx.x, w = t >> 6, l = t & 63, g = l >> 4, c = l & 15;
  const int row0 = w * 16;

  // ---- T0 load volley (order = consumption order) ----
  const int4* bp = (const int4*)bfm + (size_t)b * 4096;
  int4 bv[8];
#pragma unroll
  for (int it = 0; it < 8; ++it) bv[it] = bp[it * 512 + t];
  s16x8 mst0 = *(const s16x8*)&McT[t * 8];
  s16x8 mst1 = {0, 0, 0, 0, 0, 0, 0, 0};
  if (t < 128) mst1 = *(const s16x8*)&McT[(512 + t) * 8];
  int av = 0;
  if (t < 128) av = a_bfm[b * 128 + t];
  const float* arow = adj + (size_t)b * 16384 + (size_t)(row0 + c) * 128;
  float4 a0[4], a1[4];
#pragma unroll
  for (int kk = 0; kk < 4; ++kk) {
    a0[kk] = *(const float4*)(arow + kk * 32 + g * 8);
    a1[kk] = *(const float4*)(arow + kk * 32 + g * 8 + 4);
  }

  // ---- zero Pt (no global dep) ----
#pragma unroll
  for (int i = 0; i < 1; ++i)
    ((uint4*)Pt)[t] = make_uint4(0u, 0u, 0u, 0u);  // 512 uint4 = 8 KB

  // ---- histogram: thread covers cols (t&31)*4..+3, rows it*16+(t>>5) ----
  unsigned pA[4] = {0, 0, 0, 0}, pB[4] = {0, 0, 0, 0};
#pragma unroll
  for (int it = 0; it < 8; ++it) {
    const int vv[4] = {bv[it].x, bv[it].y, bv[it].z, bv[it].w};
#pragma unroll
    for (int jj = 0; jj < 4; ++jj) {
      pA[jj] += (unsigned)(vv[jj] == 1) + ((unsigned)(vv[jj] == 2) << 8) +
                ((unsigned)(vv[jj] == 3) << 16) + ((unsigned)(vv[jj] == 4) << 24);
      pB[jj] += (unsigned)(vv[jj] == 5);
    }
  }
#pragma unroll
  for (int jj = 0; jj < 4; ++jj) {  // lanes l, l^32 share the column set
    pA[jj] += (unsigned)__shfl_xor((int)pA[jj], 32);
    pB[jj] += (unsigned)__shfl_xor((int)pB[jj], 32);
  }
  if (l < 32) {
#pragma unroll
    for (int jj = 0; jj < 4; ++jj) {
      red[w][l][jj][0] = pA[jj];  // byte values <= 16
      red[w][l][jj][1] = pB[jj];
    }
  }
  // Mt stage (vmcnt waits only up to mst; adj stays queued)
  *(s16x8*)&Mt[t * 8] = mst0;
  if (t < 128) *(s16x8*)&Mt[(512 + t) * 8] = mst1;
  asm volatile("s_waitcnt lgkmcnt(0)" ::: "memory");
  __builtin_amdgcn_s_barrier();

  // ---- final reduce + P^T scatter, all in-LDS (j == t for t<128) ----
  if (t < 128 && av > 0) {
    unsigned A = 0, B = 0;
    const int cc = t >> 2, jj = t & 3;
#pragma unroll
    for (int w2 = 0; w2 < 8; ++w2) {
      A += red[w2][cc][jj][0];  // byte sums <= 128, no carry
      B += red[w2][cc][jj][1];
    }
    const int ai = av - 1;
    const int chunk = t >> 3, off = t & 7;
    const float cf[5] = {(float)(A & 255u), (float)((A >> 8) & 255u),
                         (float)((A >> 16) & 255u), (float)(A >> 24),
                         (float)(B & 255u)};
#pragma unroll
    for (int ei = 0; ei < 5; ++ei) {
      const int r = ei * 5 + ai;
      Pt[r * 128 + ((chunk ^ (r & 15)) << 3) + off] =
          (unsigned short)f2bf(cf[ei]);
    }
  }
  asm volatile("s_waitcnt lgkmcnt(0)" ::: "memory");
  __builtin_amdgcn_s_barrier();

  // ---- stage 1: Q = adj @ P  (2 col-tiles x 4 k-chunks = 8 MFMA) ----
  s16x8 bP[4][2];
#pragma unroll
  for (int kk = 0; kk < 4; ++kk)
#pragma unroll
    for (int ct = 0; ct < 2; ++ct) {
      const int r = ct * 16 + c;
      bP[kk][ct] = *(const s16x8*)&Pt[r * 128 + (((kk * 4 + g) ^ (r & 15)) << 3)];
    }
  // pack adj A-frags (vmcnt(0) lands here; issued at T0, covered by hist)
  s16x8 apk[4];
#pragma unroll
  for (int kk = 0; kk < 4; ++kk) {
    unsigned* pu = (unsigned*)&apk[kk];
    pu[0] = pk2(a0[kk].x, a0[kk].y);
    pu[1] = pk2(a0[kk].z, a0[kk].w);
    pu[2] = pk2(a1[kk].x, a1[kk].y);
    pu[3] = pk2(a1[kk].z, a1[kk].w);
  }
  f32x4 accQ[2] = {{0.f, 0.f, 0.f, 0.f}, {0.f, 0.f, 0.f, 0.f}};
#pragma unroll
  for (int kk = 0; kk < 4; ++kk)
#pragma unroll
    for (int ct = 0; ct < 2; ++ct)
      accQ[ct] = __builtin_amdgcn_mfma_f32_16x16x32_bf16(apk[kk], bP[kk][ct],
                                                         accQ[ct], 0, 0, 0);

  // ---- transpose Q through wave-local LDS (no cross-wave barrier) ----
  unsigned short* qsw = &Qs[w * 16 * 40];
#pragma unroll
  for (int ct = 0; ct < 2; ++ct)
#pragma unroll
    for (int q = 0; q < 4; ++q)
      qsw[(g * 4 + q) * 40 + ct * 16 + c] = (unsigned short)f2bf(accQ[ct][q]);
  const s16x8 aQ = *(const s16x8*)&qsw[c * 40 + g * 8];

  // ---- stage 2 (operand-swapped): lane (g,c) -> out[row0+c][mt*16+g*4..+3]
  float* ob = out + (size_t)b * 16384 + (size_t)(row0 + c) * 128;
#pragma unroll
  for (int mt = 0; mt < 8; ++mt) {
    const s16x8 aM = *(const s16x8*)&Mt[(mt * 16 + c) * 40 + g * 8];
    f32x4 acc2 = {0.f, 0.f, 0.f, 0.f};
    acc2 = __builtin_amdgcn_mfma_f32_16x16x32_bf16(aM, aQ, acc2, 0, 0, 0);
    *(f32x4*)(ob + mt * 16 + g * 4) = acc2;
  }
}

extern "C" void kernel_launch(void* const* d_in, const int* in_sizes, int n_in,
                              void* d_out, int out_size, void* d_ws,
                              size_t ws_size, hipStream_t stream) {
  // inputs: 0=afm(unused), 1=bfm, 2=a_bfm, 3=adj, 4=adj_w, 5=adj_a
  const int* bfm = (const int*)d_in[1];
  const int* a_bfm = (const int*)d_in[2];
  const float* adj = (const float*)d_in[3];
  const float* adj_w = (const float*)d_in[4];
  const float* adj_a = (const float*)d_in[5];
  float* out = (float*)d_out;

  unsigned short* McT = (unsigned short*)d_ws;  // 128*40 bf16 = 10.24 KB

  precomp_McT<<<dim3(80), dim3(256), 0, stream>>>(adj_w, adj_a, McT);
  fused_batch_kernel<<<dim3(256), dim3(512), 0, stream>>>(bfm, adj, a_bfm,
                                                          McT, out);
}